// Round 2
// baseline (3675.013 us; speedup 1.0000x reference)
//
#include <hip/hip_runtime.h>
#include <cstdint>

#define T_LEN 2048
#define NB    32
#define NROWS (NB*T_LEN)   // 65536
#define HH    200
#define G4    800
#define TB    256          // LSTM time-chunk

typedef _Float16 f16;
typedef _Float16 f16x2 __attribute__((ext_vector_type(2)));
typedef _Float16 f16x8 __attribute__((ext_vector_type(8)));
typedef float   floatx4 __attribute__((ext_vector_type(4)));

static __device__ __forceinline__ unsigned short f2h(float x) {
  f16 h = (f16)x; return __builtin_bit_cast(unsigned short, h);
}
static __device__ __forceinline__ float h2f(unsigned short u) {
  return (float)__builtin_bit_cast(f16, u);
}
static __device__ __forceinline__ float dot2f(unsigned int a, unsigned int b, float c) {
  return __builtin_amdgcn_fdot2(__builtin_bit_cast(f16x2, a),
                                __builtin_bit_cast(f16x2, b), c, false);
}
static __device__ __forceinline__ float sigm(float x) {
  return __builtin_amdgcn_rcpf(1.f + __expf(-x));
}
static __device__ __forceinline__ float tanh_fast(float x) {
  return 1.f - 2.f * __builtin_amdgcn_rcpf(__expf(2.f * x) + 1.f);
}

// ---------------- P/Q precompute: P[dt,co]=sum_ci relu(k1)k2, Q with relu(-k1)
__global__ void pq_kernel(const float* __restrict__ k1w, const float* __restrict__ k2w,
                          float* __restrict__ PQ) {
  int id = blockIdx.x * 256 + threadIdx.x;   // 1536 total
  int pq = id / 768;
  int rem = id % 768;
  int wdt = rem / 256;
  int co  = rem % 256;
  float acc = 0.f;
  for (int ci = 0; ci < 256; ++ci) {
    float k = k1w[ci];
    float kk = pq ? fmaxf(-k, 0.f) : fmaxf(k, 0.f);
    acc += kk * k2w[((size_t)wdt * 256 + ci) * 256 + co];
  }
  PQ[id] = acc;
}

// ---------------- misc f16 weight prep
__global__ void prep_kernel(const float* __restrict__ k3w,
                            const float* __restrict__ Wf, const float* __restrict__ bfv,
                            const float* __restrict__ Wb, const float* __restrict__ bbv,
                            unsigned short* __restrict__ K3h, unsigned short* __restrict__ Wx2,
                            unsigned short* __restrict__ WhT, float* __restrict__ bcat) {
  int id = blockIdx.x * 256 + threadIdx.x;
  if (id < 65536) { K3h[id] = f2h(k3w[id]); return; }
  id -= 65536;
  if (id < 409600) {                     // Wx2: [dir][k<256][n<800]
    int k = id / 1600, n = id % 1600;
    int dirv = (n >= 800);
    int nn = n - dirv * 800;
    const float* W = dirv ? Wb : Wf;
    Wx2[(size_t)dirv * 204800 + k * 800 + nn] = f2h(W[k * 800 + nn]);
    return;
  }
  id -= 409600;
  if (id < 320000) {                     // WhT: [dir][gate j][k] = W[256+k][j]
    int dirv = id / 160000;
    int r = id % 160000;
    int j = r / 200, k = r % 200;
    const float* W = dirv ? Wb : Wf;
    WhT[id] = f2h(W[(256 + k)*800 + j]);
    return;
  }
  id -= 320000;
  if (id < 1600) bcat[id] = (id < 800) ? bfv[id] : bbv[id - 800];
}

// ---------------- conv2 via rank-1 collapse (6 FMA/elem)
__global__ void conv2_kernel(const float* __restrict__ s, const float* __restrict__ PQ,
                             unsigned short* __restrict__ C2) {
  int row = blockIdx.x;
  int co  = threadIdx.x;
  int t = row & (T_LEN - 1);
  float s0 = s[row];
  float sm = (t > 0)         ? s[row - 1] : 0.f;
  float sp = (t < T_LEN - 1) ? s[row + 1] : 0.f;
  const float* P = PQ;
  const float* Q = PQ + 768;
  float acc = 0.f;
  float a, m;
  a = fmaxf(sm, 0.f); m = fmaxf(-sm, 0.f);
  acc += a * P[0*256+co] + m * Q[0*256+co];
  a = fmaxf(s0, 0.f); m = fmaxf(-s0, 0.f);
  acc += a * P[1*256+co] + m * Q[1*256+co];
  a = fmaxf(sp, 0.f); m = fmaxf(-sp, 0.f);
  acc += a * P[2*256+co] + m * Q[2*256+co];
  C2[(size_t)row * 256 + co] = f2h(fmaxf(acc, 0.f));
}

// ---------------- MFMA GEMM, K=256 fixed.
// mode 0: direct rows; out = relu(acc) + relu(s*k1aw+k1ab)   (conv3+conv1a -> enc)
// mode 2: gathered rows (chain/time-chunk); out = acc + bcat[dir*800+col]
__global__ __launch_bounds__(256, 2) void gemm_kernel(
    const unsigned short* __restrict__ Ag, const unsigned short* __restrict__ Bg0,
    int N, int ntiles, int mode,
    unsigned short* __restrict__ Outp,
    const float* __restrict__ bias, const float* __restrict__ Sg,
    const float* __restrict__ k1aw, const float* __restrict__ k1ab,
    const int* __restrict__ lens, int t0)
{
  __shared__ __align__(16) unsigned short Bl[128*128]; // [n][k-phase], xor-swizzled 16B chunks
  __shared__ __align__(16) unsigned short Al[128*40];  // [m][k32], pad 40 halves
  __shared__ int rowsrc[128];
  int tid = threadIdx.x;
  int tm = blockIdx.x / ntiles, tn = blockIdx.x % ntiles;
  int col0 = tn * 128;
  int lane = tid & 63, wv = tid >> 6;
  int quad = lane >> 4, l16 = lane & 15;
  int wrow = (wv & 1) * 64, wcol = (wv >> 1) * 64;

  int dirv = 0;
  if (mode == 2) dirv = ((tm * 128) >> 8) >> 5;   // chain = m/TB ; dir = chain>>5
  const unsigned short* Bg = Bg0 + (size_t)dirv * 204800;

  if (tid < 128) {
    int r;
    if (mode == 2) {
      int m = tm * 128 + tid;
      int ch = m >> 8;              // TB=256
      int ls = m & 255;
      int b = ch & 31, dd = ch >> 5;
      int L = lens[b]; L = (L < 0) ? 0 : ((L > T_LEN) ? T_LEN : L);
      int t = t0 + ls;
      int src = dd ? (L - 1 - t) : t;
      src = (src < 0) ? 0 : ((src > T_LEN - 1) ? (T_LEN - 1) : src);
      r = b * T_LEN + src;
    } else {
      r = tm * 128 + tid;
    }
    rowsrc[tid] = r;
  }

  floatx4 acc[16];
  #pragma unroll
  for (int i = 0; i < 16; ++i) acc[i] = (floatx4){0.f,0.f,0.f,0.f};

  for (int ph = 0; ph < 2; ++ph) {
    __syncthreads();
    // stage B half-panel: k in [ph*128, ph*128+128), n in [0,128)
    #pragma unroll
    for (int it = 0; it < 8; ++it) {
      int idx = it * 256 + tid;             // 2048 chunks of 8 halves
      int kin = idx >> 4;                   // k within phase 0..127
      int k = ph * 128 + kin;
      int n8 = idx & 15;
      int nb = col0 + n8 * 8;
      unsigned short vals[8];
      if (nb + 8 <= N) {
        uint4 v = *(const uint4*)(Bg + (size_t)k * N + nb);
        vals[0] = v.x & 0xffff; vals[1] = v.x >> 16;
        vals[2] = v.y & 0xffff; vals[3] = v.y >> 16;
        vals[4] = v.z & 0xffff; vals[5] = v.z >> 16;
        vals[6] = v.w & 0xffff; vals[7] = v.w >> 16;
      } else {
        #pragma unroll
        for (int j = 0; j < 8; ++j)
          vals[j] = (nb + j < N) ? Bg[(size_t)k * N + nb + j] : (unsigned short)0;
      }
      int cch = kin >> 3;
      int kof = kin & 7;
      #pragma unroll
      for (int j = 0; j < 8; ++j) {
        int n = n8 * 8 + j;
        int p = cch ^ (n & 7);
        Bl[n * 128 + p * 8 + kof] = vals[j];
      }
    }
    for (int kb2 = 0; kb2 < 4; ++kb2) {
      int kb = ph * 4 + kb2;
      __syncthreads();
      #pragma unroll
      for (int i = 0; i < 2; ++i) {
        int c2 = i * 256 + tid;
        int r = c2 >> 2, kc = (c2 & 3) * 8;
        uint4 v = *(const uint4*)(Ag + (size_t)rowsrc[r] * 256 + kb * 32 + kc);
        *(uint4*)(&Al[r * 40 + kc]) = v;
      }
      __syncthreads();
      f16x8 af[4], bfr[4];
      #pragma unroll
      for (int mt = 0; mt < 4; ++mt)
        af[mt] = *(const f16x8*)(&Al[(wrow + mt*16 + l16) * 40 + quad * 8]);
      #pragma unroll
      for (int nt = 0; nt < 4; ++nt) {
        int nl = wcol + nt*16 + l16;
        int cch = (kb & 3) * 4 + quad;
        int p = cch ^ (nl & 7);
        bfr[nt] = *(const f16x8*)(&Bl[nl * 128 + p * 8]);
      }
      #pragma unroll
      for (int mt = 0; mt < 4; ++mt)
        #pragma unroll
        for (int nt = 0; nt < 4; ++nt)
          acc[mt*4+nt] = __builtin_amdgcn_mfma_f32_16x16x32_f16(af[mt], bfr[nt], acc[mt*4+nt], 0, 0, 0);
    }
  }
  #pragma unroll
  for (int mt = 0; mt < 4; ++mt) {
    #pragma unroll
    for (int nt = 0; nt < 4; ++nt) {
      floatx4 v = acc[mt*4+nt];
      int col = col0 + wcol + nt*16 + l16;
      if (col < N) {
        #pragma unroll
        for (int r = 0; r < 4; ++r) {
          int row = tm * 128 + wrow + mt*16 + quad*4 + r;
          float x = v[r];
          float o;
          if (mode == 0) {
            float sv = Sg[row];
            float a1 = sv * k1aw[col] + k1ab[col];
            o = fmaxf(x, 0.f) + fmaxf(a1, 0.f);
          } else {
            o = x + bias[dirv * 800 + col];
          }
          Outp[(size_t)row * N + col] = f2h(o);
        }
      }
    }
  }
}

// ---------------- chunked persistent recurrent LSTM: one WG per (sample, direction)
// 448 threads: tid<400 own gates {tid, tid+400}, Wh in VGPRs (f16 pairs).
__global__ __launch_bounds__(448, 2) void lstm_kernel(
    const unsigned short* __restrict__ XWbuf,  // [64][TB][800] f16 (bias folded)
    const unsigned short* __restrict__ WhT,    // [dir][gate][k<200] f16
    const int* __restrict__ lens,
    unsigned short* __restrict__ fwH, unsigned short* __restrict__ bwH,
    float* __restrict__ cState, unsigned short* __restrict__ hState,
    int t0)
{
  int ch  = blockIdx.x;
  int dir = ch >> 5;
  int b   = ch & 31;
  int L = lens[b];
  L = (L < 0) ? 0 : ((L > T_LEN) ? T_LEN : L);
  int tend = t0 + TB; if (tend > L) tend = L;
  int tid = threadIdx.x;
  bool worker = tid < 400;
  bool stater = tid < 200;
  int g0 = tid, g1 = tid + 400;

  __shared__ __align__(16) unsigned short hbuf[2][224];
  __shared__ float zbuf[800];

  if (tid < 224) {
    unsigned short hv = 0;
    if (tid < 200 && t0 > 0) hv = hState[ch * HH + tid];
    hbuf[0][tid] = hv; hbuf[1][tid] = hv;
  }
  float c = 0.f;
  unsigned short cur_h = 0;
  if (stater && t0 > 0) { c = cState[ch * HH + tid]; cur_h = hState[ch * HH + tid]; }

  unsigned int w[200];
  if (worker) {
    const uint4* w0 = (const uint4*)(WhT + ((size_t)(dir*G4 + g0))*HH);
    const uint4* w1 = (const uint4*)(WhT + ((size_t)(dir*G4 + g1))*HH);
    #pragma unroll
    for (int r = 0; r < 25; ++r) {
      uint4 v = w0[r];
      w[4*r+0]=v.x; w[4*r+1]=v.y; w[4*r+2]=v.z; w[4*r+3]=v.w;
      uint4 u = w1[r];
      w[100+4*r+0]=u.x; w[100+4*r+1]=u.y; w[100+4*r+2]=u.z; w[100+4*r+3]=u.w;
    }
  }

  unsigned short* Hd = dir ? bwH : fwH;
  const unsigned short* XWc = XWbuf + ((size_t)ch * TB) * 800;
  float zx0 = 0.f, zx1 = 0.f;
  if (worker && t0 < tend) {
    zx0 = h2f(XWc[g0]); zx1 = h2f(XWc[g1]);
  }
  int pend_off = 0;
  unsigned short pend_hh = 0;
  bool pend_v = false;
  __syncthreads();

  for (int t = t0; t < tend; ++t) {
    // deferred global h-store from previous step (hidden behind dot phase)
    if (stater && pend_v) Hd[pend_off] = pend_hh;
    // prefetch x-projection for t+1 (consumed after dots)
    unsigned short nz0 = 0, nz1 = 0;
    int tn = t + 1;
    if (worker && tn < tend) {
      const unsigned short* p = XWc + (size_t)(tn - t0) * 800;
      nz0 = p[g0]; nz1 = p[g1];
    }
    float a0 = zx0, a1 = zx1, p0 = 0.f, p1 = 0.f;
    if (worker) {
      const uint4* hp = (const uint4*)(&hbuf[t & 1][0]);
      #pragma unroll
      for (int i = 0; i < 25; ++i) {
        uint4 hv = hp[i];
        a0 = dot2f(hv.x, w[4*i+0], a0);
        p0 = dot2f(hv.y, w[4*i+1], p0);
        a0 = dot2f(hv.z, w[4*i+2], a0);
        p0 = dot2f(hv.w, w[4*i+3], p0);
        a1 = dot2f(hv.x, w[100+4*i+0], a1);
        p1 = dot2f(hv.y, w[100+4*i+1], p1);
        a1 = dot2f(hv.z, w[100+4*i+2], a1);
        p1 = dot2f(hv.w, w[100+4*i+3], p1);
      }
      zbuf[g0] = a0 + p0;
      zbuf[g1] = a1 + p1;
    }
    __syncthreads();
    if (stater) {
      float zi = zbuf[tid];
      float zj = zbuf[tid + 200];
      float zf = zbuf[tid + 400];
      float zo = zbuf[tid + 600];
      c = c * sigm(zf + 1.f) + sigm(zi) * tanh_fast(zj);
      float h = tanh_fast(c) * sigm(zo);
      unsigned short hh = f2h(h);
      cur_h = hh;
      hbuf[(t & 1) ^ 1][tid] = hh;
      int orow = dir ? (b*T_LEN + (L - 1 - t)) : (b*T_LEN + t);
      pend_off = orow * HH + tid;
      pend_hh = hh;
      pend_v = true;
    }
    zx0 = h2f(nz0); zx1 = h2f(nz1);
    __syncthreads();
  }
  if (stater) {
    if (pend_v) Hd[pend_off] = pend_hh;
    cState[ch * HH + tid] = c;
    hState[ch * HH + tid] = cur_h;
  }
}

// ---------------- logits = [fwH|bwH] @ Wd + bd
__global__ __launch_bounds__(256) void out_kernel(
    const unsigned short* __restrict__ fwH, const unsigned short* __restrict__ bwH,
    const float* __restrict__ Wd, const float* __restrict__ bd, float* __restrict__ out)
{
  __shared__ float wd[2000];
  int tid = threadIdx.x;
  for (int i = tid; i < 2000; i += 256) wd[i] = Wd[i];
  __syncthreads();
  int row = blockIdx.x * 256 + tid;
  float acc0 = bd[0], acc1 = bd[1], acc2 = bd[2], acc3 = bd[3], acc4 = bd[4];
  const unsigned int* fu = (const unsigned int*)(fwH + (size_t)row * HH);
  const unsigned int* bu = (const unsigned int*)(bwH + (size_t)row * HH);
  #pragma unroll 4
  for (int i = 0; i < 100; ++i) {
    f16x2 pf = __builtin_bit_cast(f16x2, fu[i]);
    f16x2 pb = __builtin_bit_cast(f16x2, bu[i]);
    int k = 2 * i;
    float f0 = (float)pf[0], f1 = (float)pf[1];
    float b0 = (float)pb[0], b1 = (float)pb[1];
    const float* w0 = &wd[k*5];
    const float* w1 = &wd[(k+1)*5];
    const float* w2 = &wd[(200+k)*5];
    const float* w3 = &wd[(201+k)*5];
    acc0 += f0*w0[0] + f1*w1[0] + b0*w2[0] + b1*w3[0];
    acc1 += f0*w0[1] + f1*w1[1] + b0*w2[1] + b1*w3[1];
    acc2 += f0*w0[2] + f1*w1[2] + b0*w2[2] + b1*w3[2];
    acc3 += f0*w0[3] + f1*w1[3] + b0*w2[3] + b1*w3[3];
    acc4 += f0*w0[4] + f1*w1[4] + b0*w2[4] + b1*w3[4];
  }
  float* o = out + (size_t)row * 5;
  o[0]=acc0; o[1]=acc1; o[2]=acc2; o[3]=acc3; o[4]=acc4;
}

extern "C" void kernel_launch(void* const* d_in, const int* in_sizes, int n_in,
                              void* d_out, int out_size, void* d_ws, size_t ws_size,
                              hipStream_t stream)
{
  const float* signals = (const float*)d_in[0];
  const int*   lens    = (const int*)  d_in[1];
  const float* k1w     = (const float*)d_in[2];
  const float* k1aw    = (const float*)d_in[3];
  const float* k1ab    = (const float*)d_in[4];
  const float* k2w     = (const float*)d_in[5];
  const float* k3w     = (const float*)d_in[6];
  const float* Wf      = (const float*)d_in[7];
  const float* bf      = (const float*)d_in[8];
  const float* Wb      = (const float*)d_in[9];
  const float* bb      = (const float*)d_in[10];
  const float* Wd      = (const float*)d_in[11];
  const float* bd      = (const float*)d_in[12];
  float* out = (float*)d_out;
  char* ws = (char*)d_ws;

  // Region A aliases C2 (conv phase) and XWbuf (LSTM phase) — disjoint lifetimes.
  size_t szC2   = (size_t)NROWS * 256 * 2;          // 33,554,432
  size_t szXWb  = (size_t)64 * TB * 800 * 2;        // 26,214,400
  size_t szA    = (szC2 > szXWb) ? szC2 : szXWb;
  size_t oA   = 0;
  size_t oE   = oA   + szA;
  size_t oFw  = oE   + (size_t)NROWS*256*2;
  size_t oBw  = oFw  + (size_t)NROWS*HH*2;
  size_t oWhT = oBw  + (size_t)NROWS*HH*2;
  size_t oWx2 = oWhT + (size_t)2*800*200*2;
  size_t oK3  = oWx2 + (size_t)2*256*800*2;
  size_t oPQ  = oK3  + (size_t)256*256*2;
  size_t oBc  = oPQ  + 1536*4;
  size_t oCst = oBc  + 1600*4;
  size_t oHst = oCst + (size_t)64*HH*4;
  size_t total= oHst + (size_t)64*HH*2;             // ~115.6 MB
  if (ws_size < total) return;

  unsigned short* C2    = (unsigned short*)(ws + oA);
  unsigned short* XWbuf = (unsigned short*)(ws + oA);
  unsigned short* E     = (unsigned short*)(ws + oE);
  unsigned short* fwH   = (unsigned short*)(ws + oFw);
  unsigned short* bwH   = (unsigned short*)(ws + oBw);
  unsigned short* WhT   = (unsigned short*)(ws + oWhT);
  unsigned short* Wx2   = (unsigned short*)(ws + oWx2);
  unsigned short* K3h   = (unsigned short*)(ws + oK3);
  float* PQ     = (float*)(ws + oPQ);
  float* bcat   = (float*)(ws + oBc);
  float* cState = (float*)(ws + oCst);
  unsigned short* hState = (unsigned short*)(ws + oHst);

  hipMemsetAsync(fwH, 0, (size_t)2*NROWS*HH*2, stream);
  pq_kernel  <<<6,     256, 0, stream>>>(k1w, k2w, PQ);
  prep_kernel<<<3113,  256, 0, stream>>>(k3w, Wf, bf, Wb, bb, K3h, Wx2, WhT, bcat);
  conv2_kernel<<<NROWS, 256, 0, stream>>>(signals, PQ, C2);
  gemm_kernel<<<1024,  256, 0, stream>>>(C2, K3h, 256, 2, 0, E, nullptr, signals, k1aw, k1ab, nullptr, 0);
  for (int t0 = 0; t0 < T_LEN; t0 += TB) {
    gemm_kernel<<<896, 256, 0, stream>>>(E, Wx2, 800, 7, 2, XWbuf, bcat, nullptr, nullptr, nullptr, lens, t0);
    lstm_kernel<<<64,  448, 0, stream>>>(XWbuf, WhT, lens, fwH, bwH, cState, hState, t0);
  }
  out_kernel <<<256,   256, 0, stream>>>(fwH, bwH, Wd, bd, out);
}

// Round 3
// 3251.629 us; speedup vs baseline: 1.1302x; 1.1302x over previous
//
#include <hip/hip_runtime.h>
#include <cstdint>

#define T_LEN 2048
#define NB    32
#define NROWS (NB*T_LEN)   // 65536
#define HH    200
#define G4    800
#define TB    256          // LSTM time-chunk (per dispatch)
#define SB    16           // step block staged in LDS

typedef _Float16 f16;
typedef _Float16 f16x2 __attribute__((ext_vector_type(2)));
typedef _Float16 f16x8 __attribute__((ext_vector_type(8)));
typedef float   floatx4 __attribute__((ext_vector_type(4)));

static __device__ __forceinline__ unsigned short f2h(float x) {
  f16 h = (f16)x; return __builtin_bit_cast(unsigned short, h);
}
static __device__ __forceinline__ float h2f(unsigned short u) {
  return (float)__builtin_bit_cast(f16, u);
}
static __device__ __forceinline__ float dot2f(unsigned int a, unsigned int b, float c) {
  return __builtin_amdgcn_fdot2(__builtin_bit_cast(f16x2, a),
                                __builtin_bit_cast(f16x2, b), c, false);
}
static __device__ __forceinline__ float sigm(float x) {
  return __builtin_amdgcn_rcpf(1.f + __expf(-x));
}
static __device__ __forceinline__ float tanh_fast(float x) {
  return 1.f - 2.f * __builtin_amdgcn_rcpf(__expf(2.f * x) + 1.f);
}

// ---------------- P/Q precompute: P[dt,co]=sum_ci relu(k1)k2, Q with relu(-k1)
__global__ void pq_kernel(const float* __restrict__ k1w, const float* __restrict__ k2w,
                          float* __restrict__ PQ) {
  int id = blockIdx.x * 256 + threadIdx.x;   // 1536 total
  int pq = id / 768;
  int rem = id % 768;
  int wdt = rem / 256;
  int co  = rem % 256;
  float acc = 0.f;
  for (int ci = 0; ci < 256; ++ci) {
    float k = k1w[ci];
    float kk = pq ? fmaxf(-k, 0.f) : fmaxf(k, 0.f);
    acc += kk * k2w[((size_t)wdt * 256 + ci) * 256 + co];
  }
  PQ[id] = acc;
}

// ---------------- misc f16 weight prep
__global__ void prep_kernel(const float* __restrict__ k3w,
                            const float* __restrict__ Wf, const float* __restrict__ bfv,
                            const float* __restrict__ Wb, const float* __restrict__ bbv,
                            unsigned short* __restrict__ K3h, unsigned short* __restrict__ Wx2,
                            unsigned short* __restrict__ WhT, float* __restrict__ bcat) {
  int id = blockIdx.x * 256 + threadIdx.x;
  if (id < 65536) { K3h[id] = f2h(k3w[id]); return; }
  id -= 65536;
  if (id < 409600) {                     // Wx2: [dir][k<256][n<800]
    int k = id / 1600, n = id % 1600;
    int dirv = (n >= 800);
    int nn = n - dirv * 800;
    const float* W = dirv ? Wb : Wf;
    Wx2[(size_t)dirv * 204800 + k * 800 + nn] = f2h(W[k * 800 + nn]);
    return;
  }
  id -= 409600;
  if (id < 320000) {                     // WhT: [dir][gate j][k] = W[256+k][j]
    int dirv = id / 160000;
    int r = id % 160000;
    int j = r / 200, k = r % 200;
    const float* W = dirv ? Wb : Wf;
    WhT[id] = f2h(W[(256 + k)*800 + j]);
    return;
  }
  id -= 320000;
  if (id < 1600) bcat[id] = (id < 800) ? bfv[id] : bbv[id - 800];
}

// ---------------- conv2 via rank-1 collapse (6 FMA/elem)
__global__ void conv2_kernel(const float* __restrict__ s, const float* __restrict__ PQ,
                             unsigned short* __restrict__ C2) {
  int row = blockIdx.x;
  int co  = threadIdx.x;
  int t = row & (T_LEN - 1);
  float s0 = s[row];
  float sm = (t > 0)         ? s[row - 1] : 0.f;
  float sp = (t < T_LEN - 1) ? s[row + 1] : 0.f;
  const float* P = PQ;
  const float* Q = PQ + 768;
  float acc = 0.f;
  float a, m;
  a = fmaxf(sm, 0.f); m = fmaxf(-sm, 0.f);
  acc += a * P[0*256+co] + m * Q[0*256+co];
  a = fmaxf(s0, 0.f); m = fmaxf(-s0, 0.f);
  acc += a * P[1*256+co] + m * Q[1*256+co];
  a = fmaxf(sp, 0.f); m = fmaxf(-sp, 0.f);
  acc += a * P[2*256+co] + m * Q[2*256+co];
  C2[(size_t)row * 256 + co] = f2h(fmaxf(acc, 0.f));
}

// ---------------- MFMA GEMM, K=256 fixed.
// mode 0: direct rows; out = relu(acc) + relu(s*k1aw+k1ab)   (conv3+conv1a -> enc)
// mode 2: gathered rows (chain/time-chunk); out = acc + bcat[dir*800+col]
__global__ __launch_bounds__(256, 2) void gemm_kernel(
    const unsigned short* __restrict__ Ag, const unsigned short* __restrict__ Bg0,
    int N, int ntiles, int mode,
    unsigned short* __restrict__ Outp,
    const float* __restrict__ bias, const float* __restrict__ Sg,
    const float* __restrict__ k1aw, const float* __restrict__ k1ab,
    const int* __restrict__ lens, int t0)
{
  __shared__ __align__(16) unsigned short Bl[128*128]; // [n][k-phase], xor-swizzled 16B chunks
  __shared__ __align__(16) unsigned short Al[128*40];  // [m][k32], pad 40 halves
  __shared__ int rowsrc[128];
  int tid = threadIdx.x;
  int tm = blockIdx.x / ntiles, tn = blockIdx.x % ntiles;
  int col0 = tn * 128;
  int lane = tid & 63, wv = tid >> 6;
  int quad = lane >> 4, l16 = lane & 15;
  int wrow = (wv & 1) * 64, wcol = (wv >> 1) * 64;

  int dirv = 0;
  if (mode == 2) dirv = ((tm * 128) >> 8) >> 5;   // chain = m/TB ; dir = chain>>5
  const unsigned short* Bg = Bg0 + (size_t)dirv * 204800;

  if (tid < 128) {
    int r;
    if (mode == 2) {
      int m = tm * 128 + tid;
      int ch = m >> 8;              // TB=256
      int ls = m & 255;
      int b = ch & 31, dd = ch >> 5;
      int L = lens[b]; L = (L < 0) ? 0 : ((L > T_LEN) ? T_LEN : L);
      int t = t0 + ls;
      int src = dd ? (L - 1 - t) : t;
      src = (src < 0) ? 0 : ((src > T_LEN - 1) ? (T_LEN - 1) : src);
      r = b * T_LEN + src;
    } else {
      r = tm * 128 + tid;
    }
    rowsrc[tid] = r;
  }

  floatx4 acc[16];
  #pragma unroll
  for (int i = 0; i < 16; ++i) acc[i] = (floatx4){0.f,0.f,0.f,0.f};

  for (int ph = 0; ph < 2; ++ph) {
    __syncthreads();
    // stage B half-panel: k in [ph*128, ph*128+128), n in [0,128)
    #pragma unroll
    for (int it = 0; it < 8; ++it) {
      int idx = it * 256 + tid;             // 2048 chunks of 8 halves
      int kin = idx >> 4;                   // k within phase 0..127
      int k = ph * 128 + kin;
      int n8 = idx & 15;
      int nb = col0 + n8 * 8;
      unsigned short vals[8];
      if (nb + 8 <= N) {
        uint4 v = *(const uint4*)(Bg + (size_t)k * N + nb);
        vals[0] = v.x & 0xffff; vals[1] = v.x >> 16;
        vals[2] = v.y & 0xffff; vals[3] = v.y >> 16;
        vals[4] = v.z & 0xffff; vals[5] = v.z >> 16;
        vals[6] = v.w & 0xffff; vals[7] = v.w >> 16;
      } else {
        #pragma unroll
        for (int j = 0; j < 8; ++j)
          vals[j] = (nb + j < N) ? Bg[(size_t)k * N + nb + j] : (unsigned short)0;
      }
      int cch = kin >> 3;
      int kof = kin & 7;
      #pragma unroll
      for (int j = 0; j < 8; ++j) {
        int n = n8 * 8 + j;
        int p = cch ^ (n & 7);
        Bl[n * 128 + p * 8 + kof] = vals[j];
      }
    }
    for (int kb2 = 0; kb2 < 4; ++kb2) {
      int kb = ph * 4 + kb2;
      __syncthreads();
      #pragma unroll
      for (int i = 0; i < 2; ++i) {
        int c2 = i * 256 + tid;
        int r = c2 >> 2, kc = (c2 & 3) * 8;
        uint4 v = *(const uint4*)(Ag + (size_t)rowsrc[r] * 256 + kb * 32 + kc);
        *(uint4*)(&Al[r * 40 + kc]) = v;
      }
      __syncthreads();
      f16x8 af[4], bfr[4];
      #pragma unroll
      for (int mt = 0; mt < 4; ++mt)
        af[mt] = *(const f16x8*)(&Al[(wrow + mt*16 + l16) * 40 + quad * 8]);
      #pragma unroll
      for (int nt = 0; nt < 4; ++nt) {
        int nl = wcol + nt*16 + l16;
        int cch = (kb & 3) * 4 + quad;
        int p = cch ^ (nl & 7);
        bfr[nt] = *(const f16x8*)(&Bl[nl * 128 + p * 8]);
      }
      #pragma unroll
      for (int mt = 0; mt < 4; ++mt)
        #pragma unroll
        for (int nt = 0; nt < 4; ++nt)
          acc[mt*4+nt] = __builtin_amdgcn_mfma_f32_16x16x32_f16(af[mt], bfr[nt], acc[mt*4+nt], 0, 0, 0);
    }
  }
  #pragma unroll
  for (int mt = 0; mt < 4; ++mt) {
    #pragma unroll
    for (int nt = 0; nt < 4; ++nt) {
      floatx4 v = acc[mt*4+nt];
      int col = col0 + wcol + nt*16 + l16;
      if (col < N) {
        #pragma unroll
        for (int r = 0; r < 4; ++r) {
          int row = tm * 128 + wrow + mt*16 + quad*4 + r;
          float x = v[r];
          float o;
          if (mode == 0) {
            float sv = Sg[row];
            float a1 = sv * k1aw[col] + k1ab[col];
            o = fmaxf(x, 0.f) + fmaxf(a1, 0.f);
          } else {
            o = x + bias[dirv * 800 + col];
          }
          Outp[(size_t)row * N + col] = f2h(o);
        }
      }
    }
  }
}

// ---------------- chunked persistent recurrent LSTM: one WG per (sample, direction)
// 448 threads; worker tid<400 owns gates {2tid, 2tid+1}; Wh in VGPRs (f16 pairs).
// XW staged per 16-step block into double-buffered LDS; h history batched in LDS,
// flushed as coalesced dwordx4 once per block. Per-step barriers are lgkm-only.
__global__ __launch_bounds__(448, 2) void lstm_kernel(
    const unsigned short* __restrict__ XWbuf,  // [64][TB][800] f16 (bias folded)
    const unsigned short* __restrict__ WhT,    // [dir][gate][k<200] f16
    const int* __restrict__ lens,
    unsigned short* __restrict__ fwH, unsigned short* __restrict__ bwH,
    float* __restrict__ cState, unsigned short* __restrict__ hState,
    int t0)
{
  int ch  = blockIdx.x;
  int dir = ch >> 5;
  int b   = ch & 31;
  int L = lens[b];
  L = (L < 0) ? 0 : ((L > T_LEN) ? T_LEN : L);
  int tend = t0 + TB; if (tend > L) tend = L;
  int tid = threadIdx.x;
  bool worker = tid < 400;
  bool stater = tid < 200;

  __shared__ __align__(16) unsigned short xw_lds[2][SB*800]; // 51.2 KB
  __shared__ __align__(16) unsigned short hist[SB*200];      // 6.4 KB
  __shared__ __align__(16) unsigned short hbuf[2][224];
  __shared__ float zbuf[800];

  if (tid < 224) {
    unsigned short hv = 0;
    if (tid < 200 && t0 > 0) hv = hState[ch * HH + tid];
    hbuf[0][tid] = hv; hbuf[1][tid] = hv;
  }
  float c = 0.f;
  unsigned short cur_h = 0;
  if (stater && t0 > 0) { c = cState[ch * HH + tid]; cur_h = hState[ch * HH + tid]; }

  unsigned int w[200];   // gate 2tid in w[0..99], gate 2tid+1 in w[100..199]
  if (worker) {
    const uint4* wp = (const uint4*)(WhT + ((size_t)(dir*G4 + 2*tid))*HH);
    #pragma unroll
    for (int r = 0; r < 50; ++r) {
      uint4 v = wp[r];
      w[4*r+0]=v.x; w[4*r+1]=v.y; w[4*r+2]=v.z; w[4*r+3]=v.w;
    }
  }

  unsigned short* Hd = dir ? bwH : fwH;
  const unsigned short* XWc = XWbuf + ((size_t)ch * TB) * 800;

  uint4 r0, r1, r2, r3;   // staging regs for next block (1600 uint4 / 400 workers)
  if (worker && t0 < tend) {
    const uint4* gp = (const uint4*)XWc;
    r0 = gp[tid]; r1 = gp[tid+400]; r2 = gp[tid+800]; r3 = gp[tid+1200];
  }
  int buf = 0;
  int prev_tb = -1, prev_cnt = 0;

  for (int tb = t0; tb < tend; tb += SB) {
    int cnt = tend - tb; if (cnt > SB) cnt = SB;
    if (worker) {
      uint4* lp = (uint4*)&xw_lds[buf][0];
      lp[tid] = r0; lp[tid+400] = r1; lp[tid+800] = r2; lp[tid+1200] = r3;
    }
    __syncthreads();
    for (int sl = 0; sl < cnt; ++sl) {
      int t = tb + sl;
      if (sl == 0) {
        // issue next-block global loads (drained at next barrier, ~1 dot phase away)
        int ntb = tb + SB;
        if (worker && (ntb - t0) < TB) {
          const uint4* gp = (const uint4*)(XWc + (size_t)(ntb - t0) * 800);
          r0 = gp[tid]; r1 = gp[tid+400]; r2 = gp[tid+800]; r3 = gp[tid+1200];
        }
        // flush previous block's h history (coalesced; ack overlaps dot phase)
        if (prev_tb >= 0) {
          int pcnt = prev_cnt;
          if (tid < pcnt * 25) {
            int srow = dir ? (pcnt - 1 - tid / 25) : (tid / 25);
            uint4 v = *(const uint4*)&hist[srow*200 + (tid % 25)*8];
            size_t base = dir ? ((size_t)(b*T_LEN + (L - prev_tb - pcnt)))*HH
                              : ((size_t)(b*T_LEN + prev_tb))*HH;
            *(uint4*)(Hd + base + (size_t)tid*8) = v;
          }
        }
      }
      if (worker) {
        unsigned int xv = *(const unsigned int*)&xw_lds[buf][sl*800 + 2*tid];
        f16x2 xp = __builtin_bit_cast(f16x2, xv);
        float a0 = (float)xp[0], a1 = (float)xp[1], p0 = 0.f, p1 = 0.f;
        const uint4* hp = (const uint4*)&hbuf[t & 1][0];
        #pragma unroll
        for (int i = 0; i < 25; ++i) {
          uint4 hv = hp[i];
          a0 = dot2f(hv.x, w[4*i+0],     a0);
          p0 = dot2f(hv.y, w[4*i+1],     p0);
          a0 = dot2f(hv.z, w[4*i+2],     a0);
          p0 = dot2f(hv.w, w[4*i+3],     p0);
          a1 = dot2f(hv.x, w[100+4*i+0], a1);
          p1 = dot2f(hv.y, w[100+4*i+1], p1);
          a1 = dot2f(hv.z, w[100+4*i+2], a1);
          p1 = dot2f(hv.w, w[100+4*i+3], p1);
        }
        float2 zz; zz.x = a0 + p0; zz.y = a1 + p1;
        *(float2*)&zbuf[2*tid] = zz;
      }
      __syncthreads();
      if (stater) {
        float zi = zbuf[tid];
        float zj = zbuf[tid + 200];
        float zf = zbuf[tid + 400];
        float zo = zbuf[tid + 600];
        c = c * sigm(zf + 1.f) + sigm(zi) * tanh_fast(zj);
        float h = tanh_fast(c) * sigm(zo);
        unsigned short hh = f2h(h);
        cur_h = hh;
        hbuf[(t & 1) ^ 1][tid] = hh;
        hist[sl*200 + tid] = hh;
      }
      __syncthreads();
    }
    prev_tb = tb; prev_cnt = cnt; buf ^= 1;
  }
  // final flush + state save
  if (prev_tb >= 0) {
    int pcnt = prev_cnt;
    if (tid < pcnt * 25) {
      int srow = dir ? (pcnt - 1 - tid / 25) : (tid / 25);
      uint4 v = *(const uint4*)&hist[srow*200 + (tid % 25)*8];
      size_t base = dir ? ((size_t)(b*T_LEN + (L - prev_tb - pcnt)))*HH
                        : ((size_t)(b*T_LEN + prev_tb))*HH;
      *(uint4*)(Hd + base + (size_t)tid*8) = v;
    }
  }
  if (stater) {
    cState[ch * HH + tid] = c;
    hState[ch * HH + tid] = cur_h;
  }
}

// ---------------- logits = [fwH|bwH] @ Wd + bd
__global__ __launch_bounds__(256) void out_kernel(
    const unsigned short* __restrict__ fwH, const unsigned short* __restrict__ bwH,
    const float* __restrict__ Wd, const float* __restrict__ bd, float* __restrict__ out)
{
  __shared__ float wd[2000];
  int tid = threadIdx.x;
  for (int i = tid; i < 2000; i += 256) wd[i] = Wd[i];
  __syncthreads();
  int row = blockIdx.x * 256 + tid;
  float acc0 = bd[0], acc1 = bd[1], acc2 = bd[2], acc3 = bd[3], acc4 = bd[4];
  const unsigned int* fu = (const unsigned int*)(fwH + (size_t)row * HH);
  const unsigned int* bu = (const unsigned int*)(bwH + (size_t)row * HH);
  #pragma unroll 4
  for (int i = 0; i < 100; ++i) {
    f16x2 pf = __builtin_bit_cast(f16x2, fu[i]);
    f16x2 pb = __builtin_bit_cast(f16x2, bu[i]);
    int k = 2 * i;
    float f0 = (float)pf[0], f1 = (float)pf[1];
    float b0 = (float)pb[0], b1 = (float)pb[1];
    const float* w0 = &wd[k*5];
    const float* w1 = &wd[(k+1)*5];
    const float* w2 = &wd[(200+k)*5];
    const float* w3 = &wd[(201+k)*5];
    acc0 += f0*w0[0] + f1*w1[0] + b0*w2[0] + b1*w3[0];
    acc1 += f0*w0[1] + f1*w1[1] + b0*w2[1] + b1*w3[1];
    acc2 += f0*w0[2] + f1*w1[2] + b0*w2[2] + b1*w3[2];
    acc3 += f0*w0[3] + f1*w1[3] + b0*w2[3] + b1*w3[3];
    acc4 += f0*w0[4] + f1*w1[4] + b0*w2[4] + b1*w3[4];
  }
  float* o = out + (size_t)row * 5;
  o[0]=acc0; o[1]=acc1; o[2]=acc2; o[3]=acc3; o[4]=acc4;
}

extern "C" void kernel_launch(void* const* d_in, const int* in_sizes, int n_in,
                              void* d_out, int out_size, void* d_ws, size_t ws_size,
                              hipStream_t stream)
{
  const float* signals = (const float*)d_in[0];
  const int*   lens    = (const int*)  d_in[1];
  const float* k1w     = (const float*)d_in[2];
  const float* k1aw    = (const float*)d_in[3];
  const float* k1ab    = (const float*)d_in[4];
  const float* k2w     = (const float*)d_in[5];
  const float* k3w     = (const float*)d_in[6];
  const float* Wf      = (const float*)d_in[7];
  const float* bf      = (const float*)d_in[8];
  const float* Wb      = (const float*)d_in[9];
  const float* bb      = (const float*)d_in[10];
  const float* Wd      = (const float*)d_in[11];
  const float* bd      = (const float*)d_in[12];
  float* out = (float*)d_out;
  char* ws = (char*)d_ws;

  // Region A aliases C2 (conv phase) and XWbuf (LSTM phase) — disjoint lifetimes.
  size_t szC2   = (size_t)NROWS * 256 * 2;          // 33,554,432
  size_t szXWb  = (size_t)64 * TB * 800 * 2;        // 26,214,400
  size_t szA    = (szC2 > szXWb) ? szC2 : szXWb;
  size_t oA   = 0;
  size_t oE   = oA   + szA;
  size_t oFw  = oE   + (size_t)NROWS*256*2;
  size_t oBw  = oFw  + (size_t)NROWS*HH*2;
  size_t oWhT = oBw  + (size_t)NROWS*HH*2;
  size_t oWx2 = oWhT + (size_t)2*800*200*2;
  size_t oK3  = oWx2 + (size_t)2*256*800*2;
  size_t oPQ  = oK3  + (size_t)256*256*2;
  size_t oBc  = oPQ  + 1536*4;
  size_t oCst = oBc  + 1600*4;
  size_t oHst = oCst + (size_t)64*HH*4;
  size_t total= oHst + (size_t)64*HH*2;             // ~115.6 MB
  if (ws_size < total) return;

  unsigned short* C2    = (unsigned short*)(ws + oA);
  unsigned short* XWbuf = (unsigned short*)(ws + oA);
  unsigned short* E     = (unsigned short*)(ws + oE);
  unsigned short* fwH   = (unsigned short*)(ws + oFw);
  unsigned short* bwH   = (unsigned short*)(ws + oBw);
  unsigned short* WhT   = (unsigned short*)(ws + oWhT);
  unsigned short* Wx2   = (unsigned short*)(ws + oWx2);
  unsigned short* K3h   = (unsigned short*)(ws + oK3);
  float* PQ     = (float*)(ws + oPQ);
  float* bcat   = (float*)(ws + oBc);
  float* cState = (float*)(ws + oCst);
  unsigned short* hState = (unsigned short*)(ws + oHst);

  hipMemsetAsync(fwH, 0, (size_t)2*NROWS*HH*2, stream);
  pq_kernel  <<<6,     256, 0, stream>>>(k1w, k2w, PQ);
  prep_kernel<<<3113,  256, 0, stream>>>(k3w, Wf, bf, Wb, bb, K3h, Wx2, WhT, bcat);
  conv2_kernel<<<NROWS, 256, 0, stream>>>(signals, PQ, C2);
  gemm_kernel<<<1024,  256, 0, stream>>>(C2, K3h, 256, 2, 0, E, nullptr, signals, k1aw, k1ab, nullptr, 0);
  for (int t0 = 0; t0 < T_LEN; t0 += TB) {
    gemm_kernel<<<896, 256, 0, stream>>>(E, Wx2, 800, 7, 2, XWbuf, bcat, nullptr, nullptr, nullptr, lens, t0);
    lstm_kernel<<<64,  448, 0, stream>>>(XWbuf, WhT, lens, fwH, bwH, cState, hState, t0);
  }
  out_kernel <<<256,   256, 0, stream>>>(fwH, bwH, Wd, bd, out);
}

// Round 4
// 2969.934 us; speedup vs baseline: 1.2374x; 1.0948x over previous
//
#include <hip/hip_runtime.h>
#include <cstdint>

#define T_LEN 2048
#define NB    32
#define NROWS (NB*T_LEN)   // 65536
#define HH    200
#define G4    800
#define TB    256          // LSTM time-chunk (per dispatch)
#define SB    16           // step block staged in LDS

typedef _Float16 f16;
typedef _Float16 f16x2 __attribute__((ext_vector_type(2)));
typedef _Float16 f16x8 __attribute__((ext_vector_type(8)));
typedef float   floatx4 __attribute__((ext_vector_type(4)));

#define GLD_LDS16(g, l) __builtin_amdgcn_global_load_lds( \
    (const __attribute__((address_space(1))) void*)(g), \
    (__attribute__((address_space(3))) void*)(l), 16, 0, 0)

static __device__ __forceinline__ unsigned short f2h(float x) {
  f16 h = (f16)x; return __builtin_bit_cast(unsigned short, h);
}
static __device__ __forceinline__ float h2f(unsigned short u) {
  return (float)__builtin_bit_cast(f16, u);
}
static __device__ __forceinline__ float dot2f(unsigned int a, unsigned int b, float c) {
  return __builtin_amdgcn_fdot2(__builtin_bit_cast(f16x2, a),
                                __builtin_bit_cast(f16x2, b), c, false);
}
static __device__ __forceinline__ float sigm(float x) {
  return __builtin_amdgcn_rcpf(1.f + __expf(-x));
}
static __device__ __forceinline__ float tanh_fast(float x) {
  return 1.f - 2.f * __builtin_amdgcn_rcpf(__expf(2.f * x) + 1.f);
}

// ---------------- P/Q precompute: P[dt,co]=sum_ci relu(k1)k2, Q with relu(-k1)
__global__ void pq_kernel(const float* __restrict__ k1w, const float* __restrict__ k2w,
                          float* __restrict__ PQ) {
  int id = blockIdx.x * 256 + threadIdx.x;   // 1536 total
  int pq = id / 768;
  int rem = id % 768;
  int wdt = rem / 256;
  int co  = rem % 256;
  float acc = 0.f;
  for (int ci = 0; ci < 256; ++ci) {
    float k = k1w[ci];
    float kk = pq ? fmaxf(-k, 0.f) : fmaxf(k, 0.f);
    acc += kk * k2w[((size_t)wdt * 256 + ci) * 256 + co];
  }
  PQ[id] = acc;
}

// ---------------- f16 weight prep (B matrices stored TRANSPOSED: [n][k])
// K3T[co][ci] ; Wx2[dir][c][k] with permuted col c=4n+q (gate g=q*200+n) ;
// WhT[dir][g][k] ; bcat permuted to match c.
__global__ void prep_kernel(const float* __restrict__ k3w,
                            const float* __restrict__ Wf, const float* __restrict__ bfv,
                            const float* __restrict__ Wb, const float* __restrict__ bbv,
                            unsigned short* __restrict__ K3h, unsigned short* __restrict__ Wx2,
                            unsigned short* __restrict__ WhT, float* __restrict__ bcat) {
  int id = blockIdx.x * 256 + threadIdx.x;
  if (id < 65536) {                      // K3T[co*256+ci] = k3w[ci*256+co]
    K3h[id] = f2h(k3w[(id & 255) * 256 + (id >> 8)]);
    return;
  }
  id -= 65536;
  if (id < 409600) {                     // Wx2[dir][c<800][k<256]
    int dirv = id / 204800;
    int r = id % 204800;
    int c = r >> 8, k = r & 255;
    int n = c >> 2, q = c & 3;
    int g = q * 200 + n;
    const float* W = dirv ? Wb : Wf;
    Wx2[id] = f2h(W[k * 800 + g]);
    return;
  }
  id -= 409600;
  if (id < 320000) {                     // WhT: [dir][gate g][k] = W[256+k][g]
    int dirv = id / 160000;
    int r = id % 160000;
    int g = r / 200, k = r % 200;
    const float* W = dirv ? Wb : Wf;
    WhT[id] = f2h(W[(256 + k)*800 + g]);
    return;
  }
  id -= 320000;
  if (id < 1600) {                       // bcat[dir*800 + c] with same perm
    int dirv = id / 800;
    int c = id % 800;
    int n = c >> 2, q = c & 3;
    int g = q * 200 + n;
    bcat[id] = (dirv ? bbv : bfv)[g];
  }
}

// ---------------- conv2 via rank-1 collapse (6 FMA/elem)
__global__ void conv2_kernel(const float* __restrict__ s, const float* __restrict__ PQ,
                             unsigned short* __restrict__ C2) {
  int row = blockIdx.x;
  int co  = threadIdx.x;
  int t = row & (T_LEN - 1);
  float s0 = s[row];
  float sm = (t > 0)         ? s[row - 1] : 0.f;
  float sp = (t < T_LEN - 1) ? s[row + 1] : 0.f;
  const float* P = PQ;
  const float* Q = PQ + 768;
  float acc = 0.f;
  float a, m;
  a = fmaxf(sm, 0.f); m = fmaxf(-sm, 0.f);
  acc += a * P[0*256+co] + m * Q[0*256+co];
  a = fmaxf(s0, 0.f); m = fmaxf(-s0, 0.f);
  acc += a * P[1*256+co] + m * Q[1*256+co];
  a = fmaxf(sp, 0.f); m = fmaxf(-sp, 0.f);
  acc += a * P[2*256+co] + m * Q[2*256+co];
  C2[(size_t)row * 256 + co] = f2h(fmaxf(acc, 0.f));
}

// ---------------- MFMA GEMM, K=256 fixed. B given TRANSPOSED [n][256].
// mode 0: direct rows; out = relu(acc) + relu(s*k1aw+k1ab)   (conv3+conv1a -> enc)
// mode 2: gathered rows (chain/time-chunk); out = acc + bcat[dir*800+col]
__global__ __launch_bounds__(256, 2) void gemm_kernel(
    const unsigned short* __restrict__ Ag, const unsigned short* __restrict__ Bg0,
    int N, int ntiles, int mode,
    unsigned short* __restrict__ Outp,
    const float* __restrict__ bias, const float* __restrict__ Sg,
    const float* __restrict__ k1aw, const float* __restrict__ k1ab,
    const int* __restrict__ lens, int t0)
{
  __shared__ __align__(16) unsigned short Bl[128*128]; // [n][k-phase], xor-swizzled 16B chunks
  __shared__ __align__(16) unsigned short Al[128*40];  // [m][k32], pad 40 halves
  __shared__ int rowsrc[128];
  int tid = threadIdx.x;
  int tm = blockIdx.x / ntiles, tn = blockIdx.x % ntiles;
  int col0 = tn * 128;
  int lane = tid & 63, wv = tid >> 6;
  int quad = lane >> 4, l16 = lane & 15;
  int wrow = (wv & 1) * 64, wcol = (wv >> 1) * 64;

  int dirv = 0;
  if (mode == 2) dirv = ((tm * 128) >> 8) >> 5;   // chain = m/TB ; dir = chain>>5
  const unsigned short* Bg = Bg0 + (size_t)dirv * 204800;

  if (tid < 128) {
    int r;
    if (mode == 2) {
      int m = tm * 128 + tid;
      int ch = m >> 8;              // TB=256
      int ls = m & 255;
      int b = ch & 31, dd = ch >> 5;
      int L = lens[b]; L = (L < 0) ? 0 : ((L > T_LEN) ? T_LEN : L);
      int t = t0 + ls;
      int src = dd ? (L - 1 - t) : t;
      src = (src < 0) ? 0 : ((src > T_LEN - 1) ? (T_LEN - 1) : src);
      r = b * T_LEN + src;
    } else {
      r = tm * 128 + tid;
    }
    rowsrc[tid] = r;
  }

  floatx4 acc[16];
  #pragma unroll
  for (int i = 0; i < 16; ++i) acc[i] = (floatx4){0.f,0.f,0.f,0.f};

  for (int ph = 0; ph < 2; ++ph) {
    __syncthreads();
    // stage B half-panel from BT: rows n in [col0,col0+128), k in [ph*128, +128)
    #pragma unroll
    for (int it = 0; it < 8; ++it) {
      int idx = it * 256 + tid;             // 2048 b128 chunks
      int n  = idx >> 4;                    // 0..127 local col
      int k8 = idx & 15;                    // 16B chunk within phase
      int nn = col0 + n;
      uint4 v = (uint4){0u,0u,0u,0u};
      if (nn < N) v = *(const uint4*)(Bg + (size_t)nn * 256 + ph * 128 + k8 * 8);
      *(uint4*)(&Bl[n * 128 + ((k8 ^ (n & 7)) * 8)]) = v;
    }
    for (int kb2 = 0; kb2 < 4; ++kb2) {
      int kb = ph * 4 + kb2;
      __syncthreads();
      #pragma unroll
      for (int i = 0; i < 2; ++i) {
        int c2 = i * 256 + tid;
        int r = c2 >> 2, kc = (c2 & 3) * 8;
        uint4 v = *(const uint4*)(Ag + (size_t)rowsrc[r] * 256 + kb * 32 + kc);
        *(uint4*)(&Al[r * 40 + kc]) = v;
      }
      __syncthreads();
      f16x8 af[4], bfr[4];
      #pragma unroll
      for (int mt = 0; mt < 4; ++mt)
        af[mt] = *(const f16x8*)(&Al[(wrow + mt*16 + l16) * 40 + quad * 8]);
      #pragma unroll
      for (int nt = 0; nt < 4; ++nt) {
        int nl = wcol + nt*16 + l16;
        int c = kb2 * 4 + quad;
        bfr[nt] = *(const f16x8*)(&Bl[nl * 128 + ((c ^ (nl & 7)) * 8)]);
      }
      #pragma unroll
      for (int mt = 0; mt < 4; ++mt)
        #pragma unroll
        for (int nt = 0; nt < 4; ++nt)
          acc[mt*4+nt] = __builtin_amdgcn_mfma_f32_16x16x32_f16(af[mt], bfr[nt], acc[mt*4+nt], 0, 0, 0);
    }
  }
  #pragma unroll
  for (int mt = 0; mt < 4; ++mt) {
    #pragma unroll
    for (int nt = 0; nt < 4; ++nt) {
      floatx4 v = acc[mt*4+nt];
      int col = col0 + wcol + nt*16 + l16;
      if (col < N) {
        #pragma unroll
        for (int r = 0; r < 4; ++r) {
          int row = tm * 128 + wrow + mt*16 + quad*4 + r;
          float x = v[r];
          float o;
          if (mode == 0) {
            float sv = Sg[row];
            float a1 = sv * k1aw[col] + k1ab[col];
            o = fmaxf(x, 0.f) + fmaxf(a1, 0.f);
          } else {
            o = x + bias[dirv * 800 + col];
          }
          Outp[(size_t)row * N + col] = f2h(o);
        }
      }
    }
  }
}

// ---------------- chunked persistent recurrent LSTM: one WG per (sample, direction)
// 448 threads; worker tid<400: p = tid/200, n = tid%200, owns gates q=2p,2p+1 of
// unit n (g = q*200+n). Wh in VGPRs (200 dwords, amdgpu_waves_per_eu(2,2) to keep
// them arch-resident). XW DMA'd to LDS via global_load_lds (no staging VGPRs).
// Activation computed redundantly by both p-replicas (one float2 LDS exchange).
__global__ __launch_bounds__(448) __attribute__((amdgpu_waves_per_eu(2, 2)))
void lstm_kernel(
    const unsigned short* __restrict__ XWbuf,  // [64][TB][800] f16, cols permuted c=4n+q, bias folded
    const unsigned short* __restrict__ WhT,    // [dir][gate g][k<200] f16
    const int* __restrict__ lens,
    unsigned short* __restrict__ fwH, unsigned short* __restrict__ bwH,
    float* __restrict__ cState, unsigned short* __restrict__ hState,
    int t0)
{
  int ch  = blockIdx.x;
  int dir = ch >> 5;
  int b   = ch & 31;
  int L = lens[b];
  L = (L < 0) ? 0 : ((L > T_LEN) ? T_LEN : L);
  int tend = t0 + TB; if (tend > L) tend = L;
  int tid = threadIdx.x;
  bool worker = tid < 400;
  int p = (tid >= 200) ? 1 : 0;        // meaningful for workers
  int n = tid - p * 200;               // unit index (workers)
  bool writer = tid < 200;

  __shared__ __align__(16) unsigned short xw_lds[2][SB*800]; // 51.2 KB
  __shared__ __align__(16) unsigned short hist[SB*200];      // 6.4 KB
  __shared__ __align__(16) unsigned short hbuf[224];
  __shared__ float2 zpair[400];                              // [p*200+n]

  if (tid < 224) {
    unsigned short hv = 0;
    if (tid < 200 && t0 > 0) hv = hState[ch * HH + tid];
    hbuf[tid] = hv;
  }
  float c = 0.f;
  if (worker && t0 > 0) c = cState[ch * HH + n];
  unsigned short cur_h = 0;
  if (writer && t0 > 0) cur_h = hState[ch * HH + tid];

  unsigned int w[200];   // gate q=2p rows in w[0..99], q=2p+1 in w[100..199]
  if (worker) {
    const uint4* w0 = (const uint4*)(WhT + ((size_t)(dir*G4 + (2*p)*200 + n))*HH);
    const uint4* w1 = (const uint4*)(WhT + ((size_t)(dir*G4 + (2*p+1)*200 + n))*HH);
    #pragma unroll
    for (int r = 0; r < 25; ++r) {
      uint4 v = w0[r];
      w[4*r+0]=v.x; w[4*r+1]=v.y; w[4*r+2]=v.z; w[4*r+3]=v.w;
      uint4 u = w1[r];
      w[100+4*r+0]=u.x; w[100+4*r+1]=u.y; w[100+4*r+2]=u.z; w[100+4*r+3]=u.w;
    }
  }

  unsigned short* Hd = dir ? bwH : fwH;
  const unsigned short* XWc = XWbuf + ((size_t)ch * TB) * 800;

  // DMA block 0 into xw_lds[0] (16B chunks; wave-uniform base + lane*16)
  if (t0 < tend) {
    #pragma unroll
    for (int it = 0; it < 4; ++it) {
      int cidx = it * 448 + tid;
      if (cidx < 1600)
        GLD_LDS16(XWc + (size_t)cidx * 8, &xw_lds[0][cidx * 8]);
    }
  }
  int buf = 0;
  int prev_tb = -1, prev_cnt = 0;

  for (int tb = t0; tb < tend; tb += SB) {
    int cnt = tend - tb; if (cnt > SB) cnt = SB;
    __syncthreads();   // drains DMA for this block (vmcnt) + orders hist reuse
    for (int sl = 0; sl < cnt; ++sl) {
      if (sl == 0) {
        // DMA next block into the other buffer (drained at next block's barrier)
        int ntb = tb + SB;
        if ((ntb - t0) < TB) {
          const unsigned short* src = XWc + (size_t)(ntb - t0) * 800;
          #pragma unroll
          for (int it = 0; it < 4; ++it) {
            int cidx = it * 448 + tid;
            if (cidx < 1600)
              GLD_LDS16(src + (size_t)cidx * 8, &xw_lds[buf ^ 1][cidx * 8]);
          }
        }
        // flush previous block's h history (coalesced; ack overlaps dot phase)
        if (prev_tb >= 0) {
          int pcnt = prev_cnt;
          if (tid < pcnt * 25) {
            int srow = dir ? (pcnt - 1 - tid / 25) : (tid / 25);
            uint4 v = *(const uint4*)&hist[srow*200 + (tid % 25)*8];
            size_t base = dir ? ((size_t)(b*T_LEN + (L - prev_tb - pcnt)))*HH
                              : ((size_t)(b*T_LEN + prev_tb))*HH;
            *(uint4*)(Hd + base + (size_t)tid*8) = v;
          }
        }
      }
      float a0 = 0.f, a1 = 0.f;
      if (worker) {
        unsigned int xv = *(const unsigned int*)&xw_lds[buf][sl*800 + 4*n + 2*p];
        f16x2 xp = __builtin_bit_cast(f16x2, xv);
        a0 = (float)xp[0]; a1 = (float)xp[1];
        float p0 = 0.f, p1 = 0.f;
        const uint4* hp = (const uint4*)&hbuf[0];
        #pragma unroll
        for (int i = 0; i < 25; ++i) {
          uint4 hv = hp[i];
          a0 = dot2f(hv.x, w[4*i+0],     a0);
          p0 = dot2f(hv.y, w[4*i+1],     p0);
          a0 = dot2f(hv.z, w[4*i+2],     a0);
          p0 = dot2f(hv.w, w[4*i+3],     p0);
          a1 = dot2f(hv.x, w[100+4*i+0], a1);
          p1 = dot2f(hv.y, w[100+4*i+1], p1);
          a1 = dot2f(hv.z, w[100+4*i+2], a1);
          p1 = dot2f(hv.w, w[100+4*i+3], p1);
        }
        a0 += p0; a1 += p1;
        float2 zz; zz.x = a0; zz.y = a1;
        zpair[tid] = zz;
      }
      __syncthreads();
      if (worker) {
        float2 zo2 = zpair[(p ^ 1) * 200 + n];
        float zi = p ? zo2.x : a0;
        float zj = p ? zo2.y : a1;
        float zf = p ? a0 : zo2.x;
        float zo = p ? a1 : zo2.y;
        c = c * sigm(zf + 1.f) + sigm(zi) * tanh_fast(zj);
        float h = tanh_fast(c) * sigm(zo);
        unsigned short hh = f2h(h);
        if (p == 0) {
          cur_h = hh;
          hbuf[n] = hh;
          hist[sl*200 + n] = hh;
        }
      }
      __syncthreads();
    }
    prev_tb = tb; prev_cnt = cnt; buf ^= 1;
  }
  // final flush + state save
  if (prev_tb >= 0) {
    int pcnt = prev_cnt;
    if (tid < pcnt * 25) {
      int srow = dir ? (pcnt - 1 - tid / 25) : (tid / 25);
      uint4 v = *(const uint4*)&hist[srow*200 + (tid % 25)*8];
      size_t base = dir ? ((size_t)(b*T_LEN + (L - prev_tb - pcnt)))*HH
                        : ((size_t)(b*T_LEN + prev_tb))*HH;
      *(uint4*)(Hd + base + (size_t)tid*8) = v;
    }
  }
  if (writer) {
    cState[ch * HH + tid] = c;
    hState[ch * HH + tid] = cur_h;
  }
}

// ---------------- logits = [fwH|bwH] @ Wd + bd
__global__ __launch_bounds__(256) void out_kernel(
    const unsigned short* __restrict__ fwH, const unsigned short* __restrict__ bwH,
    const float* __restrict__ Wd, const float* __restrict__ bd, float* __restrict__ out)
{
  __shared__ float wd[2000];
  int tid = threadIdx.x;
  for (int i = tid; i < 2000; i += 256) wd[i] = Wd[i];
  __syncthreads();
  int row = blockIdx.x * 256 + tid;
  float acc0 = bd[0], acc1 = bd[1], acc2 = bd[2], acc3 = bd[3], acc4 = bd[4];
  const unsigned int* fu = (const unsigned int*)(fwH + (size_t)row * HH);
  const unsigned int* bu = (const unsigned int*)(bwH + (size_t)row * HH);
  #pragma unroll 4
  for (int i = 0; i < 100; ++i) {
    f16x2 pf = __builtin_bit_cast(f16x2, fu[i]);
    f16x2 pb = __builtin_bit_cast(f16x2, bu[i]);
    int k = 2 * i;
    float f0 = (float)pf[0], f1 = (float)pf[1];
    float b0 = (float)pb[0], b1 = (float)pb[1];
    const float* w0 = &wd[k*5];
    const float* w1 = &wd[(k+1)*5];
    const float* w2 = &wd[(200+k)*5];
    const float* w3 = &wd[(201+k)*5];
    acc0 += f0*w0[0] + f1*w1[0] + b0*w2[0] + b1*w3[0];
    acc1 += f0*w0[1] + f1*w1[1] + b0*w2[1] + b1*w3[1];
    acc2 += f0*w0[2] + f1*w1[2] + b0*w2[2] + b1*w3[2];
    acc3 += f0*w0[3] + f1*w1[3] + b0*w2[3] + b1*w3[3];
    acc4 += f0*w0[4] + f1*w1[4] + b0*w2[4] + b1*w3[4];
  }
  float* o = out + (size_t)row * 5;
  o[0]=acc0; o[1]=acc1; o[2]=acc2; o[3]=acc3; o[4]=acc4;
}

extern "C" void kernel_launch(void* const* d_in, const int* in_sizes, int n_in,
                              void* d_out, int out_size, void* d_ws, size_t ws_size,
                              hipStream_t stream)
{
  const float* signals = (const float*)d_in[0];
  const int*   lens    = (const int*)  d_in[1];
  const float* k1w     = (const float*)d_in[2];
  const float* k1aw    = (const float*)d_in[3];
  const float* k1ab    = (const float*)d_in[4];
  const float* k2w     = (const float*)d_in[5];
  const float* k3w     = (const float*)d_in[6];
  const float* Wf      = (const float*)d_in[7];
  const float* bf      = (const float*)d_in[8];
  const float* Wb      = (const float*)d_in[9];
  const float* bb      = (const float*)d_in[10];
  const float* Wd      = (const float*)d_in[11];
  const float* bd      = (const float*)d_in[12];
  float* out = (float*)d_out;
  char* ws = (char*)d_ws;

  // Region A aliases C2 (conv phase) and XWbuf (LSTM phase) — disjoint lifetimes.
  size_t szC2   = (size_t)NROWS * 256 * 2;          // 33,554,432
  size_t szXWb  = (size_t)64 * TB * 800 * 2;        // 26,214,400
  size_t szA    = (szC2 > szXWb) ? szC2 : szXWb;
  size_t oA   = 0;
  size_t oE   = oA   + szA;
  size_t oFw  = oE   + (size_t)NROWS*256*2;
  size_t oBw  = oFw  + (size_t)NROWS*HH*2;
  size_t oWhT = oBw  + (size_t)NROWS*HH*2;
  size_t oWx2 = oWhT + (size_t)2*800*200*2;
  size_t oK3  = oWx2 + (size_t)2*256*800*2;
  size_t oPQ  = oK3  + (size_t)256*256*2;
  size_t oBc  = oPQ  + 1536*4;
  size_t oCst = oBc  + 1600*4;
  size_t oHst = oCst + (size_t)64*HH*4;
  size_t total= oHst + (size_t)64*HH*2;             // ~115.6 MB
  if (ws_size < total) return;

  unsigned short* C2    = (unsigned short*)(ws + oA);
  unsigned short* XWbuf = (unsigned short*)(ws + oA);
  unsigned short* E     = (unsigned short*)(ws + oE);
  unsigned short* fwH   = (unsigned short*)(ws + oFw);
  unsigned short* bwH   = (unsigned short*)(ws + oBw);
  unsigned short* WhT   = (unsigned short*)(ws + oWhT);
  unsigned short* Wx2   = (unsigned short*)(ws + oWx2);
  unsigned short* K3h   = (unsigned short*)(ws + oK3);
  float* PQ     = (float*)(ws + oPQ);
  float* bcat   = (float*)(ws + oBc);
  float* cState = (float*)(ws + oCst);
  unsigned short* hState = (unsigned short*)(ws + oHst);

  hipMemsetAsync(fwH, 0, (size_t)2*NROWS*HH*2, stream);
  pq_kernel  <<<6,     256, 0, stream>>>(k1w, k2w, PQ);
  prep_kernel<<<3113,  256, 0, stream>>>(k3w, Wf, bf, Wb, bb, K3h, Wx2, WhT, bcat);
  conv2_kernel<<<NROWS, 256, 0, stream>>>(signals, PQ, C2);
  gemm_kernel<<<1024,  256, 0, stream>>>(C2, K3h, 256, 2, 0, E, nullptr, signals, k1aw, k1ab, nullptr, 0);
  for (int t0 = 0; t0 < T_LEN; t0 += TB) {
    gemm_kernel<<<896, 256, 0, stream>>>(E, Wx2, 800, 7, 2, XWbuf, bcat, nullptr, nullptr, nullptr, lens, t0);
    lstm_kernel<<<64,  448, 0, stream>>>(XWbuf, WhT, lens, fwH, bwH, cState, hState, t0);
  }
  out_kernel <<<256,   256, 0, stream>>>(fwH, bwH, Wd, bd, out);
}